// Round 1
// baseline (686.606 us; speedup 1.0000x reference)
//
#include <hip/hip_runtime.h>
#include <stdint.h>

typedef unsigned int u32;
typedef unsigned long long u64;

#define BIMG 8
#define NPROP 4000
#define NCLS 91
#define CM1 90
#define MCAND (NPROP * CM1)      // 360000 candidates per image
#define KPRE 2048
#define NBUCKET 4096
#define SELCAP 16384
#define DETS 100
#define SCORE_T 0.05f
#define NMS_T 0.5f
#define BBOX_CLIP 4.135166556742356f   // log(1000/16)

// ---------------- workspace layout ----------------
#define HIST_OFF   ((size_t)0)                               // u32[8][4096]
#define BCNT_OFF   (HIST_OFF + (size_t)BIMG * NBUCKET * 4)   // u32[8][4096]
#define META_OFF   (BCNT_OFF + (size_t)BIMG * NBUCKET * 4)   // u32[8][8]: V, T, fillneed
#define ZERO_BYTES (META_OFF + 4096)
#define START_OFF  (ZERO_BYTES)                              // u32[8][4096]
#define SEL_OFF    (START_OFF + (size_t)BIMG * NBUCKET * 4)  // u64[8][SELCAP]
#define TBOX_OFF   (SEL_OFF + (size_t)BIMG * SELCAP * 8)     // f32[8][2048][4]
#define TSB_OFF    (TBOX_OFF + (size_t)BIMG * KPRE * 16)     // f32[8][2048][4] shifted
#define TSC_OFF    (TSB_OFF + (size_t)BIMG * KPRE * 16)      // f32[8][2048]
#define TLB_OFF    (TSC_OFF + (size_t)BIMG * KPRE * 4)       // i32[8][2048]
#define TVL_OFF    (TLB_OFF + (size_t)BIMG * KPRE * 4)       // u32[8][2048]
#define KEEP_OFF   (TVL_OFF + (size_t)BIMG * KPRE * 4)       // u64[8][32]
#define MASK_OFF   (KEEP_OFF + (size_t)BIMG * 32 * 8)        // u64[8][2048][32]
#define CAND_OFF   (MASK_OFF + (size_t)BIMG * KPRE * 32 * 8) // u32[8][360000]
#define WS_NEED    (CAND_OFF + (size_t)BIMG * MCAND * 4)

__device__ __forceinline__ void decode_clip(const float4 rg, const float w, const float h,
                                            const float cx, const float cy,
                                            const float fw, const float fh, float bx[4]) {
    float dx = rg.x / 10.0f;
    float dy = rg.y / 10.0f;
    float dw = fminf(rg.z / 5.0f, BBOX_CLIP);
    float dh = fminf(rg.w / 5.0f, BBOX_CLIP);
    float pcx = dx * w + cx;
    float pcy = dy * h + cy;
    float pw  = expf(dw) * w;
    float phh = expf(dh) * h;
    bx[0] = fminf(fmaxf(pcx - 0.5f * pw,  0.0f), fw);
    bx[1] = fminf(fmaxf(pcy - 0.5f * phh, 0.0f), fh);
    bx[2] = fminf(fmaxf(pcx + 0.5f * pw,  0.0f), fw);
    bx[3] = fminf(fmaxf(pcy + 0.5f * phh, 0.0f), fh);
}

// K1: one wave per proposal row. Softmax(91), decode+clip 90 class boxes,
// validity mask; store order-preserving score bits (0 = invalid) and histogram
// valid candidates into 4096 buckets (top 12 bits of ord).
__global__ __launch_bounds__(256) void k1_score_hist(
    const float* __restrict__ logits, const float* __restrict__ reg,
    const float* __restrict__ props, const int* __restrict__ imh, const int* __restrict__ imw,
    u32* __restrict__ hist, u32* __restrict__ cand_ord) {
    const int lane = threadIdx.x & 63;
    const int pid = blockIdx.x * 4 + (threadIdx.x >> 6);
    if (pid >= BIMG * NPROP) return;
    const int img = pid / NPROP;
    const float fw = (float)imw[0], fh = (float)imh[0];
    const float* lrow = logits + (size_t)pid * NCLS;
    float v0 = lrow[lane];
    float v1 = (lane < 27) ? lrow[lane + 64] : -3.0e38f;
    float mx = fmaxf(v0, v1);
#pragma unroll
    for (int o = 32; o > 0; o >>= 1) mx = fmaxf(mx, __shfl_xor(mx, o));
    float es = expf(v0 - mx) + ((lane < 27) ? expf(v1 - mx) : 0.0f);
#pragma unroll
    for (int o = 32; o > 0; o >>= 1) es += __shfl_xor(es, o);
    float4 p = reinterpret_cast<const float4*>(props)[pid];
    const float w = p.z - p.x, h = p.w - p.y;
    const float cx = p.x + 0.5f * w, cy = p.y + 0.5f * h;
    const float4* rrow = reinterpret_cast<const float4*>(reg) + (size_t)pid * NCLS;
    u32* co = cand_ord + (size_t)img * MCAND + (size_t)(pid - img * NPROP) * CM1;
#pragma unroll
    for (int batch = 0; batch < 2; ++batch) {
        int ci = lane + batch * 64;
        if (ci < CM1) {
            int c = ci + 1;
            float sc = expf(lrow[c] - mx) / es;
            float4 rg = rrow[c];
            float bx[4];
            decode_clip(rg, w, h, cx, cy, fw, fh, bx);
            bool valid = (sc > SCORE_T) && (bx[2] - bx[0] >= 1.0f) && (bx[3] - bx[1] >= 1.0f);
            u32 o = 0u;
            if (valid) {
                o = __float_as_uint(sc) | 0x80000000u;  // sc > 0 always
                atomicAdd(&hist[img * NBUCKET + (o >> 20)], 1u);
            }
            co[ci] = o;
        }
    }
}

// K2: one wave per image. Reverse (descending-bucket) exclusive scan of the
// histogram -> start[], threshold bucket T straddling rank KPRE, V, fillneed.
__global__ __launch_bounds__(64) void k2_scan(
    const u32* __restrict__ hist, u32* __restrict__ start, u32* __restrict__ meta) {
    const int img = blockIdx.x;
    const int lane = threadIdx.x;
    u32 base = 0;
    int T = -1;
    for (int chunk = 63; chunk >= 0; --chunk) {
        int bucket = chunk * 64 + 63 - lane;   // lane order = descending bucket
        u32 cnt = hist[img * NBUCKET + bucket];
        u32 inc = cnt;
#pragma unroll
        for (int o = 1; o < 64; o <<= 1) {
            u32 t = __shfl_up(inc, o);
            if (lane >= o) inc += t;
        }
        u32 excl = base + inc - cnt;
        start[img * NBUCKET + bucket] = excl;
        bool cross = (cnt > 0) && (excl < KPRE) && (excl + cnt >= KPRE);
        u64 bal = __ballot(cross);
        if (T < 0 && bal != 0ull) {
            int l = __ffsll(bal) - 1;
            T = chunk * 64 + 63 - l;
        }
        base += __shfl(inc, 63);
    }
    if (lane == 0) {
        meta[img * 8 + 0] = base;                                  // V = total valid
        meta[img * 8 + 1] = (T >= 0) ? (u32)T : 0u;                // threshold bucket
        meta[img * 8 + 2] = (base < KPRE) ? (KPRE - base) : 0u;    // fill needed
    }
}

// K3: compact candidates in buckets >= T into sel[], placed at bucket-start +
// within-bucket atomic position. Key = ord<<32 | ~idx (desc value, asc index).
__global__ __launch_bounds__(256) void k3_compact(
    const u32* __restrict__ cand_ord, const u32* __restrict__ start,
    const u32* __restrict__ meta, u32* __restrict__ bcnt, u64* __restrict__ sel) {
    const u32 t = blockIdx.x * 256 + threadIdx.x;
    if (t >= (u32)(BIMG * MCAND)) return;
    const int img = t / MCAND;
    const u32 idx = t - (u32)img * MCAND;
    const u32 o = cand_ord[t];
    if (!o) return;
    const u32 bk = o >> 20;
    if (bk < meta[img * 8 + 1]) return;
    const u32 pos = start[img * NBUCKET + bk] + atomicAdd(&bcnt[img * NBUCKET + bk], 1u);
    if (pos < SELCAP)
        sel[(size_t)img * SELCAP + pos] = ((u64)o << 32) | (u32)(~idx);
}

// K3b: rare path — fewer than KPRE valid: fill remaining slots with invalid
// candidates (score -1) in ascending-index order (lax.top_k tie semantics).
__global__ __launch_bounds__(64) void k3b_fill(
    const u32* __restrict__ cand_ord, const u32* __restrict__ meta, u64* __restrict__ sel) {
    const int img = blockIdx.x;
    const u32 need = meta[img * 8 + 2];
    if (need == 0) return;
    const u32 V = meta[img * 8 + 0];
    const int lane = threadIdx.x;
    const u32 ORDN1 = 0x407FFFFFu;  // ord_of(-1.0f)
    u32 filled = 0;
    for (u32 b0 = 0; b0 < MCAND && filled < need; b0 += 64) {
        u32 idx = b0 + lane;
        bool inv = (idx < MCAND) && (cand_ord[(size_t)img * MCAND + idx] == 0u);
        u64 bal = __ballot(inv);
        u32 pre = (u32)__popcll(bal & ((1ull << lane) - 1ull));
        if (inv && (filled + pre) < need)
            sel[(size_t)img * SELCAP + V + filled + pre] = ((u64)ORDN1 << 32) | (u32)(~idx);
        filled += (u32)__popcll(bal);
    }
}

// K4: sort each compacted bucket segment (those intersecting the top-KPRE
// region) descending by key via LDS bitonic. Segments are disjoint and already
// in global descending-bucket order, so afterwards sel[0..2047] is the exact
// top-2048 in lax.top_k order.
__global__ __launch_bounds__(256) void k4_sortseg(
    const u32* __restrict__ hist, const u32* __restrict__ start, u64* __restrict__ sel) {
    __shared__ u64 arr[4096];
    const int img = blockIdx.y;
    const int tid = threadIdx.x;
    for (int bk = blockIdx.x * 64; bk < blockIdx.x * 64 + 64; ++bk) {
        u32 cnt = hist[img * NBUCKET + bk];          // uniform across block
        if (cnt < 2) continue;
        u32 st = start[img * NBUCKET + bk];
        if (st >= KPRE) continue;                    // below top region
        if (st + cnt > SELCAP) cnt = SELCAP - st;
        if (cnt > 4096) cnt = 4096;                  // pathological only
        int n = 1;
        while (n < (int)cnt) n <<= 1;
        u64* seg = sel + (size_t)img * SELCAP + st;
        for (int i = tid; i < n; i += 256) arr[i] = (i < (int)cnt) ? seg[i] : 0ull;
        __syncthreads();
        for (int k = 2; k <= n; k <<= 1)
            for (int j = k >> 1; j > 0; j >>= 1) {
                for (int i = tid; i < n; i += 256) {
                    int ixj = i ^ j;
                    if (ixj > i) {
                        u64 a = arr[i], b = arr[ixj];
                        bool swp = ((i & k) == 0) ? (a < b) : (a > b);
                        if (swp) { arr[i] = b; arr[ixj] = a; }
                    }
                }
                __syncthreads();
            }
        for (int i = tid; i < (int)cnt; i += 256) seg[i] = arr[i];
        __syncthreads();
    }
}

// K5: gather the top-2048: re-decode boxes, store score/label/valid, compute
// max coordinate and class-offset shifted boxes exactly as the reference.
__global__ __launch_bounds__(256) void k5_gather(
    const u64* __restrict__ sel, const float* __restrict__ reg, const float* __restrict__ props,
    const int* __restrict__ imh, const int* __restrict__ imw,
    float* __restrict__ tbox, float* __restrict__ tsb, float* __restrict__ tsc,
    int* __restrict__ tlb, u32* __restrict__ tvl) {
    const int img = blockIdx.x;
    const int tid = threadIdx.x;
    const float fw = (float)imw[0], fh = (float)imh[0];
    float bx[8][4];
    int lab[8];
    float lm = -3.0e38f;
#pragma unroll
    for (int t = 0; t < 8; ++t) {
        int s = t * 256 + tid;
        u64 key = sel[(size_t)img * SELCAP + s];
        u32 o = (u32)(key >> 32);
        u32 idx = ~((u32)key);
        u32 b = (o & 0x80000000u) ? (o & 0x7FFFFFFFu) : ~o;
        float sc = __uint_as_float(b);               // exact masked score roundtrip
        u32 n = idx / CM1;
        int c = (int)(idx - n * CM1) + 1;
        int pid = img * NPROP + (int)n;
        float4 p = reinterpret_cast<const float4*>(props)[pid];
        float w = p.z - p.x, h = p.w - p.y;
        float cx = p.x + 0.5f * w, cy = p.y + 0.5f * h;
        float4 rg = reinterpret_cast<const float4*>(reg)[(size_t)pid * NCLS + c];
        decode_clip(rg, w, h, cx, cy, fw, fh, bx[t]);
        lab[t] = c;
        lm = fmaxf(lm, fmaxf(fmaxf(bx[t][0], bx[t][1]), fmaxf(bx[t][2], bx[t][3])));
        reinterpret_cast<float4*>(tbox)[(size_t)img * KPRE + s] =
            make_float4(bx[t][0], bx[t][1], bx[t][2], bx[t][3]);
        tsc[(size_t)img * KPRE + s] = sc;
        tlb[(size_t)img * KPRE + s] = c;
        tvl[(size_t)img * KPRE + s] = (sc > SCORE_T) ? 1u : 0u;
    }
#pragma unroll
    for (int o2 = 32; o2 > 0; o2 >>= 1) lm = fmaxf(lm, __shfl_xor(lm, o2));
    __shared__ float wm[4];
    if ((tid & 63) == 0) wm[tid >> 6] = lm;
    __syncthreads();
    float mplus = fmaxf(fmaxf(wm[0], wm[1]), fmaxf(wm[2], wm[3])) + 1.0f;
#pragma unroll
    for (int t = 0; t < 8; ++t) {
        int s = t * 256 + tid;
        float off = (float)lab[t] * mplus;
        reinterpret_cast<float4*>(tsb)[(size_t)img * KPRE + s] =
            make_float4(bx[t][0] + off, bx[t][1] + off, bx[t][2] + off, bx[t][3] + off);
    }
}

// K6: suppression bitmask. Block = 64 rows x 64 cols; bit set iff
// iou(shifted_i, shifted_j) > thresh and j > i (reference formula verbatim).
__global__ __launch_bounds__(64) void k6_mask(
    const float* __restrict__ tsb, u64* __restrict__ mask) {
    const int img = blockIdx.z;
    const int j0 = blockIdx.x * 64;
    const int i0 = blockIdx.y * 64;
    const int tid = threadIdx.x;
    __shared__ float4 cb[64];
    __shared__ float ca[64];
    float4 c = reinterpret_cast<const float4*>(tsb)[(size_t)img * KPRE + j0 + tid];
    cb[tid] = c;
    ca[tid] = (c.z - c.x) * (c.w - c.y);
    __syncthreads();
    const int i = i0 + tid;
    float4 r = reinterpret_cast<const float4*>(tsb)[(size_t)img * KPRE + i];
    float ra = (r.z - r.x) * (r.w - r.y);
    u64 bits = 0ull;
#pragma unroll 8
    for (int jj = 0; jj < 64; ++jj) {
        int j = j0 + jj;
        float4 cc = cb[jj];
        float wv = fmaxf(fminf(r.z, cc.z) - fmaxf(r.x, cc.x), 0.0f);
        float hv = fmaxf(fminf(r.w, cc.w) - fmaxf(r.y, cc.y), 0.0f);
        float inter = wv * hv;
        float iou = inter / ((ra + ca[jj]) - inter);   // NaN compares false, like jnp
        if ((iou > NMS_T) && (j > i)) bits |= (1ull << jj);
    }
    mask[((size_t)img * KPRE + i) * 32 + (j0 >> 6)] = bits;
}

// K7: greedy scan. One wave per image; 2048-bit removed mask lives in lanes
// 0..31 (u64 each). Rolling register prefetch of mask rows (depth 16).
__global__ __launch_bounds__(64) void k7_nms(
    const u64* __restrict__ mask, const u32* __restrict__ tvl, u64* __restrict__ keepw) {
    const int img = blockIdx.x;
    const int lane = threadIdx.x;
    u64 removed = ~0ull;
    for (int w = 0; w < 32; ++w) {
        bool tv = tvl[(size_t)img * KPRE + w * 64 + lane] != 0u;
        u64 bal = __ballot(tv);
        if (lane == w) removed = ~bal;   // invalid = pre-removed
    }
    constexpr int PD = 16;
    u64 buf[PD];
    const u64* mrow = mask + (size_t)img * KPRE * 32;
#pragma unroll
    for (int t = 0; t < PD; ++t) buf[t] = (lane < 32) ? mrow[(size_t)t * 32 + lane] : 0ull;
    for (int base = 0; base < KPRE; base += PD) {
#pragma unroll
        for (int u = 0; u < PD; ++u) {
            const int i = base + u;
            u64 rw = __shfl(removed, i >> 6);
            if (!((rw >> (i & 63)) & 1ull)) {        // i kept -> suppress its row
                if (lane < 32) removed |= buf[u];
            }
            const int nx = i + PD;
            buf[u] = (nx < KPRE && lane < 32) ? mrow[(size_t)nx * 32 + lane] : 0ull;
        }
    }
    if (lane < 32) keepw[img * 32 + lane] = ~removed;
}

// K8: final top-100 per image (bitonic over 2048 keys) + output writes.
__global__ __launch_bounds__(256) void k8_final(
    const u64* __restrict__ keepw, const float* __restrict__ tsc,
    const float* __restrict__ tbox, const int* __restrict__ tlb,
    float* __restrict__ out) {
    __shared__ u64 arr[KPRE];
    const int img = blockIdx.x;
    const int tid = threadIdx.x;
#pragma unroll
    for (int t = 0; t < 8; ++t) {
        int s = t * 256 + tid;
        u64 kw = keepw[img * 32 + (s >> 6)];
        bool kept = (kw >> (s & 63)) & 1ull;
        float ks = kept ? tsc[(size_t)img * KPRE + s] : -1.0f;
        u32 b = __float_as_uint(ks);
        u32 o = (b & 0x80000000u) ? ~b : (b | 0x80000000u);
        arr[s] = ((u64)o << 32) | (u32)(~(u32)s);
    }
    __syncthreads();
    for (int k = 2; k <= KPRE; k <<= 1)
        for (int j = k >> 1; j > 0; j >>= 1) {
            for (int i = tid; i < KPRE; i += 256) {
                int ixj = i ^ j;
                if (ixj > i) {
                    u64 a = arr[i], bb = arr[ixj];
                    bool swp = ((i & k) == 0) ? (a < bb) : (a > bb);
                    if (swp) { arr[i] = bb; arr[ixj] = a; }
                }
            }
            __syncthreads();
        }
    if (tid < DETS) {
        u64 key = arr[tid];
        u32 o = (u32)(key >> 32);
        u32 b = (o & 0x80000000u) ? (o & 0x7FFFFFFFu) : ~o;
        float fs = __uint_as_float(b);
        u32 s = ~((u32)key);
        bool fv = fs > SCORE_T;
        float4 bxv = make_float4(0.0f, 0.0f, 0.0f, 0.0f);
        float lb = -1.0f, scw = 0.0f;
        if (fv) {
            bxv = reinterpret_cast<const float4*>(tbox)[(size_t)img * KPRE + s];
            lb = (float)tlb[(size_t)img * KPRE + s];
            scw = fs;
        }
        float* ob = out + (size_t)img * DETS * 4 + (size_t)tid * 4;
        ob[0] = bxv.x; ob[1] = bxv.y; ob[2] = bxv.z; ob[3] = bxv.w;
        out[BIMG * DETS * 4 + img * DETS + tid] = scw;   // scores at 3200
        out[BIMG * DETS * 5 + img * DETS + tid] = lb;    // labels at 4000
    }
}

extern "C" void kernel_launch(void* const* d_in, const int* in_sizes, int n_in,
                              void* d_out, int out_size, void* d_ws, size_t ws_size,
                              hipStream_t stream) {
    const float* logits = (const float*)d_in[0];
    const float* reg    = (const float*)d_in[1];
    const float* props  = (const float*)d_in[2];
    const int*   imh    = (const int*)d_in[3];
    const int*   imw    = (const int*)d_in[4];
    float* out = (float*)d_out;
    char* ws = (char*)d_ws;
    if (ws_size < WS_NEED) return;  // ~17.1 MB needed

    u32* hist = (u32*)(ws + HIST_OFF);
    u32* bcnt = (u32*)(ws + BCNT_OFF);
    u32* meta = (u32*)(ws + META_OFF);
    u32* start = (u32*)(ws + START_OFF);
    u64* sel  = (u64*)(ws + SEL_OFF);
    float* tbox = (float*)(ws + TBOX_OFF);
    float* tsb  = (float*)(ws + TSB_OFF);
    float* tsc  = (float*)(ws + TSC_OFF);
    int*   tlb  = (int*)(ws + TLB_OFF);
    u32*   tvl  = (u32*)(ws + TVL_OFF);
    u64*   keepw = (u64*)(ws + KEEP_OFF);
    u64*   mask = (u64*)(ws + MASK_OFF);
    u32*   cand_ord = (u32*)(ws + CAND_OFF);

    hipMemsetAsync(d_ws, 0, ZERO_BYTES, stream);  // hist, bcnt, meta

    k1_score_hist<<<BIMG * NPROP / 4, 256, 0, stream>>>(logits, reg, props, imh, imw,
                                                        hist, cand_ord);
    k2_scan<<<BIMG, 64, 0, stream>>>(hist, start, meta);
    k3_compact<<<(BIMG * MCAND) / 256, 256, 0, stream>>>(cand_ord, start, meta, bcnt, sel);
    k3b_fill<<<BIMG, 64, 0, stream>>>(cand_ord, meta, sel);
    k4_sortseg<<<dim3(64, BIMG), 256, 0, stream>>>(hist, start, sel);
    k5_gather<<<BIMG, 256, 0, stream>>>(sel, reg, props, imh, imw, tbox, tsb, tsc, tlb, tvl);
    k6_mask<<<dim3(32, 32, BIMG), 64, 0, stream>>>(tsb, mask);
    k7_nms<<<BIMG, 64, 0, stream>>>(mask, tvl, keepw);
    k8_final<<<BIMG, 256, 0, stream>>>(keepw, tsc, tbox, tlb, out);
}